// Round 14
// baseline (322.992 us; speedup 1.0000x reference)
//
#include <hip/hip_runtime.h>
#include <stdint.h>

typedef _Float16 f16;
typedef _Float16 half8 __attribute__((ext_vector_type(8)));
typedef _Float16 half4 __attribute__((ext_vector_type(4)));
typedef __fp16 fp16x2 __attribute__((ext_vector_type(2)));
typedef float f32x4 __attribute__((ext_vector_type(4)));
typedef float f32x16 __attribute__((ext_vector_type(16)));
typedef uint32_t u32x4 __attribute__((ext_vector_type(4)));

static constexpr int Bsz = 2, S = 2048, E = 2048, H = 16, D = 128;
static constexpr int M = Bsz * S;        // 4096
static constexpr int N_QKV = 3 * H * D;  // 6144
static constexpr int HD = H * D;         // 2048

__device__ __forceinline__ void gload_lds16(const void* gp, void* lp) {
  __builtin_amdgcn_global_load_lds(
      (const __attribute__((address_space(1))) uint32_t*)(uintptr_t)gp,
      (__attribute__((address_space(3))) uint32_t*)(uint32_t)(uintptr_t)lp,
      16, 0, 0);
}

__device__ __forceinline__ uint32_t pkrtz(float a, float b) {
  fp16x2 r = __builtin_amdgcn_cvt_pkrtz(a, b);
  return __builtin_bit_cast(uint32_t, r);
}

// ---------- f32 -> f16 cast ----------
__global__ void cast_f32_f16(const float* __restrict__ in, f16* __restrict__ out) {
  size_t i = (size_t)(blockIdx.x * 256 + threadIdx.x) * 8;
  float4 a = *(const float4*)&in[i];
  float4 b = *(const float4*)&in[i + 4];
  half8 h;
  h[0] = (f16)a.x; h[1] = (f16)a.y; h[2] = (f16)a.z; h[3] = (f16)a.w;
  h[4] = (f16)b.x; h[5] = (f16)b.y; h[6] = (f16)b.z; h[7] = (f16)b.w;
  *(half8*)&out[i] = h;
}

// ---------- transpose 2048x2048 f32 [k][n] -> f16 [n][k] ----------
__global__ void transpose_cast(const float* __restrict__ wq, const float* __restrict__ wk,
                               const float* __restrict__ wv, const float* __restrict__ wo,
                               f16* __restrict__ wt, f16* __restrict__ wot) {
  __shared__ float tile[32][33];
  int z = blockIdx.z;
  const float* src = (z == 0) ? wq : (z == 1) ? wk : (z == 2) ? wv : wo;
  f16* dst = (z == 3) ? wot : wt + (size_t)z * E * HD;
  int bx = blockIdx.x * 32, by = blockIdx.y * 32;
  int tx = threadIdx.x, ty = threadIdx.y;
#pragma unroll
  for (int r = 0; r < 4; ++r)
    tile[ty + r * 8][tx] = src[(size_t)(by + ty + r * 8) * 2048 + bx + tx];
  __syncthreads();
#pragma unroll
  for (int r = 0; r < 4; ++r)
    dst[(size_t)(bx + ty + r * 8) * 2048 + by + tx] = (f16)tile[tx][ty + r * 8];
}

// ====== fused QKV: 256x384 8-phase GEMM, all-swapped mfma, fused rope/split ======
// Grid 16x16 = 256 = exactly 1 round. 512 thr = 8 waves (2M x 4N); per-wave 128x96.
// LDS 112KB: A[2buf][2kh][256][32] (64K) + B[1buf][2kh][384][32] (48K).
// Per K-tile: 4 phases x 24 MFMA; stages: A(T+1,kh1)@p1, B(T+1,kh0)@p2,
// A(T+1,kh0)@p3, B(T+1,kh1)@p4; vmcnt(5)@p2, vmcnt(3)@p4 (traced), VM0 at T=31.
#define ABUF(b_, kh_) ((b_) * 16384 + (kh_) * 8192)
#define BBUF(kh_) (32768 + (kh_) * 12288)
#define STAGE_A(T_, kh_)                                                     \
  do {                                                                       \
    int ko_ = (T_) * 64 + (kh_) * 32;                                        \
    int bb_ = (T_) & 1;                                                      \
    gload_lds16(Abase + ko_ + ca0, &lds[ABUF(bb_, kh_) + t * 8]);            \
    gload_lds16(Abase + ko_ + ca1, &lds[ABUF(bb_, kh_) + 4096 + t * 8]);     \
  } while (0)
#define STAGE_B(T_, kh_)                                                     \
  do {                                                                       \
    int ko_ = (T_) * 64 + (kh_) * 32;                                        \
    gload_lds16(Bb0 + ko_, &lds[BBUF(kh_) + t * 8]);                         \
    gload_lds16(Bb1 + ko_, &lds[BBUF(kh_) + 4096 + t * 8]);                  \
    gload_lds16(Bb2 + ko_, &lds[BBUF(kh_) + 8192 + t * 8]);                  \
  } while (0)
#define LDA4(mh_, kh_)                                                       \
  _Pragma("unroll") for (int i2 = 0; i2 < 4; ++i2) {                         \
    int ra = wm * 128 + ((mh_)*4 + i2) * 16 + lr;                            \
    int s_ = g ^ ((ra >> 2) & 3);                                            \
    af[i2] = *(const half8*)&lds[ABUF(cb, kh_) + (s_ >> 1) * 4096 + ra * 16 + (s_ & 1) * 8]; \
  }
#define LDB6(kh_)                                                            \
  _Pragma("unroll") for (int j = 0; j < 6; ++j) {                            \
    int rb = (j >> 1) * 128 + wn * 16 + (j & 1) * 64 + lr;                   \
    bf[j] = *(const half8*)&lds[BBUF(kh_) + rb * 32 + ((g ^ (rb & 3)) * 8)]; \
  }
#define MM24(mh_)                                                            \
  __builtin_amdgcn_s_setprio(1);                                             \
  _Pragma("unroll") for (int i2 = 0; i2 < 4; ++i2)                           \
  _Pragma("unroll") for (int j = 0; j < 6; ++j)                              \
      acc[(mh_)*4 + i2][j] =                                                 \
          __builtin_amdgcn_mfma_f32_16x16x32_f16(bf[j], af[i2], acc[(mh_)*4 + i2][j], 0, 0, 0); \
  __builtin_amdgcn_s_setprio(0);
#define BAR() __builtin_amdgcn_s_barrier()
#define VM5() asm volatile("s_waitcnt vmcnt(5)" ::: "memory")
#define VM3() asm volatile("s_waitcnt vmcnt(3)" ::: "memory")
#define VM0() asm volatile("s_waitcnt vmcnt(0)" ::: "memory")

__global__ __launch_bounds__(512, 1) void qkv384(const f16* __restrict__ A,
                                                 const f16* __restrict__ Bt,
                                                 const float* __restrict__ cosb,
                                                 const float* __restrict__ sinb,
                                                 f16* __restrict__ Qb,
                                                 f16* __restrict__ Kb,
                                                 f16* __restrict__ Vb) {
  __shared__ f16 lds[57344];  // 112KB
  const int Kk = E;
  const int t = threadIdx.x, l = t & 63, wid = t >> 6;
  const int wm = wid >> 2, wn = wid & 3;
  const int lr = l & 15, g = l >> 4;
  const int bid = blockIdx.x;
  const int idx = bid >> 3;
  const int bm = (bid & 7) * 2 + (idx & 1);  // 0..15, A-panels L2-resident per XCD
  const int bn = idx >> 1;                   // 0..15
  // A staging (R13-proven)
  const int arow = t >> 1, ah = t & 1;
  const int fa = (arow >> 2) & 3;
  const int ca0 = (ah ^ fa) * 8;
  const int ca1 = ((2 | ah) ^ fa) * 8;
  const f16* Abase = A + (size_t)(bm * 256 + arow) * Kk;
  // B staging: 3 gloads x 128 rows per kh-half
  const int brow = t >> 2, bch = t & 3;
  const int cb0 = ((bch ^ (brow & 3)) * 8);
  const f16* Bb0 = Bt + (size_t)(bn * 384 + brow) * Kk + cb0;
  const f16* Bb1 = Bt + (size_t)(bn * 384 + 128 + brow) * Kk + cb0;
  const f16* Bb2 = Bt + (size_t)(bn * 384 + 256 + brow) * Kk + cb0;
  const int b = bm >> 3;
  const int sblk = (bm & 7) * 256;

  f32x4 acc[8][6] = {};
  // prologue: tile0 (A kh0,kh1; B kh0,kh1) = 10 loads; need A0kh0+B0kh0 -> VM3
  STAGE_A(0, 0); STAGE_A(0, 1);
  STAGE_B(0, 0); STAGE_B(0, 1);
  VM3();
  BAR();

  for (int T = 0; T < 32; ++T) {
    const int cb = T & 1;
    half8 af[4], bf[6];
    // p1: kh0 mh0 | stage A(T+1,kh1) -> buf^1
    LDB6(0); LDA4(0, 0);
    if (T + 1 < 32) STAGE_A(T + 1, 1);
    BAR(); MM24(0); BAR();
    // p2: kh0 mh1 | stage B(T+1,kh0) (kh0 region free after p1 barrier) | VM5
    LDA4(1, 0);
    if (T + 1 < 32) STAGE_B(T + 1, 0);
    if (T == 31) { VM0(); } else { VM5(); }
    BAR(); MM24(1); BAR();
    // p3: kh1 mh0 | stage A(T+1,kh0) -> buf^1
    LDB6(1); LDA4(0, 1);
    if (T + 1 < 32) STAGE_A(T + 1, 0);
    BAR(); MM24(0); BAR();
    // p4: kh1 mh1 | stage B(T+1,kh1) | VM3
    LDA4(1, 1);
    if (T + 1 < 32) STAGE_B(T + 1, 1);
    if (T == 31) { VM0(); } else { VM3(); }
    BAR(); MM24(1); BAR();
  }

  // Epilogue (swapped C/D): thread holds 4 consecutive d at fixed s.
  // j-pair a: cols n128 = bn*384 + a*128; acc[mi][2a] = d in [dlo,dlo+4),
  // acc[mi][2a+1] = d+64. Region: 0=Q (rope), 1=K (rope), 2=V (plain->Vb).
  const int dlo = wn * 16 + g * 4;
#pragma unroll
  for (int mi = 0; mi < 8; ++mi) {
    const int s = sblk + wm * 128 + mi * 16 + lr;
    const size_t cbase = (size_t)s * D;
    float4 cl = *(const float4*)&cosb[cbase + dlo];
    float4 ch = *(const float4*)&cosb[cbase + dlo + 64];
    float4 sl = *(const float4*)&sinb[cbase + dlo];
    float4 sh = *(const float4*)&sinb[cbase + dlo + 64];
    float cla[4] = {cl.x, cl.y, cl.z, cl.w}, cha[4] = {ch.x, ch.y, ch.z, ch.w};
    float sla[4] = {sl.x, sl.y, sl.z, sl.w}, sha[4] = {sh.x, sh.y, sh.z, sh.w};
#pragma unroll
    for (int a = 0; a < 3; ++a) {
      const int n128 = bn * 384 + a * 128;
      const int region = n128 >> 11;
      const int h = (n128 >> 7) & 15;
      const int bh = b * 16 + h;
      const size_t obase = ((size_t)bh * S + s) * D;
      if (region < 2) {
        f16* Dst = (region == 0) ? Qb : Kb;
        half4 olo, ohi;
#pragma unroll
        for (int r = 0; r < 4; ++r) {
          float xl = acc[mi][2 * a][r], xh = acc[mi][2 * a + 1][r];
          olo[r] = (f16)(xl * cla[r] - xh * sla[r]);
          ohi[r] = (f16)(xh * cha[r] + xl * sha[r]);
        }
        *(half4*)&Dst[obase + dlo] = olo;
        *(half4*)&Dst[obase + dlo + 64] = ohi;
      } else {
        half4 vlo, vhi;
#pragma unroll
        for (int r = 0; r < 4; ++r) {
          vlo[r] = (f16)acc[mi][2 * a][r];
          vhi[r] = (f16)acc[mi][2 * a + 1][r];
        }
        *(half4*)&Vb[obase + dlo] = vlo;
        *(half4*)&Vb[obase + dlo + 64] = vhi;
      }
    }
  }
}
#undef ABUF
#undef BBUF
#undef STAGE_A
#undef STAGE_B
#undef LDA4
#undef LDB6
#undef MM24
#undef VM5
#undef VM3
#undef VM0
#undef BAR

// ---------- V transpose: Vb [bh][s][d] -> VtG [bh][d][s] ----------
__global__ void transpose_v(const f16* __restrict__ Vb, f16* __restrict__ VtG) {
  __shared__ f16 tl[64][136];
  int bid = blockIdx.x;
  int bh = bid >> 5, st = bid & 31;
  int t = threadIdx.x;
  int s0 = st * 64;
#pragma unroll
  for (int rnd = 0; rnd < 4; ++rnd) {
    int row = rnd * 16 + (t >> 4);
    int ch = t & 15;
    half8 v = *(const half8*)&Vb[((size_t)bh * S + s0 + row) * D + ch * 8];
    *(half8*)&tl[row][ch * 8] = v;
  }
  __syncthreads();
#pragma unroll
  for (int rnd = 0; rnd < 4; ++rnd) {
    int d = rnd * 32 + (t >> 3);
    int ch = t & 7;
    half8 v;
#pragma unroll
    for (int j = 0; j < 8; ++j) v[j] = tl[ch * 8 + j][d];
    *(half8*)&VtG[((size_t)bh * D + d) * S + s0 + ch * 8] = v;
  }
}

// Staging of one 32-k section (out-proj GEMM).
#define STAGE4(PTR, BASE, KOFF, DST)                                       \
  gload_lds16(&PTR[BASE + (KOFF) + scol], &DST[t * 8]);                    \
  gload_lds16(&PTR[BASE + (size_t)64 * Kk + (KOFF) + scol], &DST[2048 + t * 8]);

// ---------- out-proj GEMM: 128x128 BK=64; bm L2-resident per XCD ----------
template <typename OutT>
__global__ __launch_bounds__(256, 4) void gemm_bt(const f16* __restrict__ A,
                                                  const f16* __restrict__ Bt,
                                                  OutT* __restrict__ C,
                                                  int Nn, int Kk) {
  __shared__ f16 As[8192];
  __shared__ f16 Bs[8192];
  const int t = threadIdx.x, l = t & 63;
  const int wm = (t >> 7) & 1, wn = (t >> 6) & 1;
  const int bid = blockIdx.x;
  const int bm = (bid & 7) * 4 + ((bid >> 3) & 3);
  const int bn = bid >> 5;
  const int lr = l & 15, g = l >> 4;
  const int srow = t >> 2;
  const int scol = (((t & 3) ^ (srow & 3)) * 8);
  const size_t abase = (size_t)(bm * 128 + srow) * Kk;
  const size_t bbase = (size_t)(bn * 128 + srow) * Kk;
  f32x4 acc[4][4] = {};
  for (int k0 = 0; k0 < Kk; k0 += 64) {
    __syncthreads();
    STAGE4(A, abase, k0, As);
    STAGE4(Bt, bbase, k0, Bs);
    STAGE4(A, abase, k0 + 32, (As + 4096));
    STAGE4(Bt, bbase, k0 + 32, (Bs + 4096));
    __syncthreads();
#pragma unroll
    for (int kh = 0; kh < 2; ++kh) {
      const int so = kh * 4096;
      half8 af[4], bf[4];
#pragma unroll
      for (int i = 0; i < 4; ++i) {
        int ra = wm * 64 + i * 16 + lr;
        int rb = wn * 64 + i * 16 + lr;
        af[i] = *(const half8*)&As[so + ra * 32 + ((g ^ (ra & 3)) * 8)];
        bf[i] = *(const half8*)&Bs[so + rb * 32 + ((g ^ (rb & 3)) * 8)];
      }
#pragma unroll
      for (int i = 0; i < 4; ++i)
#pragma unroll
        for (int j = 0; j < 4; ++j)
          acc[i][j] = __builtin_amdgcn_mfma_f32_16x16x32_f16(af[i], bf[j], acc[i][j], 0, 0, 0);
    }
  }
#pragma unroll
  for (int i = 0; i < 4; ++i)
#pragma unroll
    for (int j = 0; j < 4; ++j) {
      int row = bm * 128 + wm * 64 + i * 16 + g * 4;
      int col = bn * 128 + wn * 64 + j * 16 + lr;
#pragma unroll
      for (int r = 0; r < 4; ++r)
        C[(size_t)(row + r) * Nn + col] = (OutT)acc[i][j][r];
    }
}

// ---------- flash attention: 32x32x16, swapped operands, defer-max ----------
__device__ __forceinline__ void stage_kv(const f16* __restrict__ Kg, const f16* __restrict__ Vg,
                                         f16* KsB, f16* VsB, int t, int kv) {
#pragma unroll
  for (int rnd = 0; rnd < 4; ++rnd) {
    int row = rnd * 16 + (t >> 4);
    int c = t & 15;
    gload_lds16(&Kg[(size_t)(kv + row) * D + ((c ^ (row & 7)) * 8)], &KsB[rnd * 2048 + t * 8]);
  }
#pragma unroll
  for (int rnd = 0; rnd < 4; ++rnd) {
    int row = rnd * 32 + (t >> 3);
    int c = t & 7;
    gload_lds16(&Vg[(size_t)row * S + kv + ((c ^ (row & 7)) * 8)], &VsB[rnd * 2048 + t * 8]);
  }
}

__global__ __launch_bounds__(256, 2) void flash_attn2(const f16* __restrict__ Q,
                                                      const f16* __restrict__ K,
                                                      const f16* __restrict__ Vt,
                                                      f16* __restrict__ O) {
  __shared__ f16 lds[2][16384];
  const int t = threadIdx.x, l = t & 63, w = t >> 6;
  const int c = l & 31, hi = l >> 5;
  int bid = blockIdx.x;
  bid = (bid & 7) * 64 + (bid >> 3);
  const int bh = bid >> 4, qt = bid & 15;
  const size_t baseQ = (size_t)bh * S * D;
  const f16* Kg = K + baseQ;
  const f16* Vg = Vt + (size_t)bh * D * S;
  const int q0 = qt * 128 + w * 32;
  half8 qf[8];
#pragma unroll
  for (int dc = 0; dc < 8; ++dc)
    qf[dc] = *(const half8*)&Q[baseQ + (size_t)(q0 + c) * D + dc * 16 + hi * 8];
  f32x16 o[4] = {};
  float m = -3.0e38f, ssum = 0.f;

  stage_kv(Kg, Vg, &lds[0][0], &lds[0][8192], t, 0);
  __syncthreads();

  for (int it = 0; it < S / 64; ++it) {
    const int cur = it & 1;
    const f16* KsB = &lds[cur][0];
    const f16* VsB = &lds[cur][8192];
    if (it + 1 < S / 64) stage_kv(Kg, Vg, &lds[cur ^ 1][0], &lds[cur ^ 1][8192], t, (it + 1) * 64);

    f32x16 s0 = {}, s1 = {};
    __builtin_amdgcn_s_setprio(1);
#pragma unroll
    for (int dc = 0; dc < 8; ++dc) {
      const int r0 = c, r1 = 32 + c;
      half8 kf0 = *(const half8*)&KsB[r0 * 128 + (((2 * dc + hi) ^ (r0 & 7)) * 8)];
      half8 kf1 = *(const half8*)&KsB[r1 * 128 + (((2 * dc + hi) ^ (r1 & 7)) * 8)];
      s0 = __builtin_amdgcn_mfma_f32_32x32x16_f16(kf0, qf[dc], s0, 0, 0, 0);
      s1 = __builtin_amdgcn_mfma_f32_32x32x16_f16(kf1, qf[dc], s1, 0, 0, 0);
    }
    __builtin_amdgcn_s_setprio(0);

    float tm = s0[0];
#pragma unroll
    for (int r = 1; r < 16; ++r) tm = fmaxf(tm, s0[r]);
#pragma unroll
    for (int r = 0; r < 16; ++r) tm = fmaxf(tm, s1[r]);
    tm = fmaxf(tm, __shfl_xor(tm, 32));
    if (!__all(tm <= m + 8.f)) {
      float mn = fmaxf(m, tm);
      float corr = __expf(m - mn);
      m = mn;
      ssum *= corr;
#pragma unroll
      for (int dt = 0; dt < 4; ++dt)
#pragma unroll
        for (int r = 0; r < 16; ++r) o[dt][r] *= corr;
    }
    float ts = 0.f;
#pragma unroll
    for (int r = 0; r < 16; ++r) { s0[r] = __expf(s0[r] - m); ts += s0[r]; }
#pragma unroll
    for (int r = 0; r < 16; ++r) { s1[r] = __expf(s1[r] - m); ts += s1[r]; }
    ts += __shfl_xor(ts, 32);
    ssum += ts;

    half8 pf[4];
#pragma unroll
    for (int ks = 0; ks < 4; ++ks) {
      const int B0 = 2 * (ks & 1), B1 = B0 + 1;
      uint32_t X0, X1, Y0, Y1;
      if (ks < 2) {
        X0 = pkrtz(s0[4 * B0 + 0], s0[4 * B0 + 1]);
        X1 = pkrtz(s0[4 * B0 + 2], s0[4 * B0 + 3]);
        Y0 = pkrtz(s0[4 * B1 + 0], s0[4 * B1 + 1]);
        Y1 = pkrtz(s0[4 * B1 + 2], s0[4 * B1 + 3]);
      } else {
        X0 = pkrtz(s1[4 * B0 + 0], s1[4 * B0 + 1]);
        X1 = pkrtz(s1[4 * B0 + 2], s1[4 * B0 + 3]);
        Y0 = pkrtz(s1[4 * B1 + 0], s1[4 * B1 + 1]);
        Y1 = pkrtz(s1[4 * B1 + 2], s1[4 * B1 + 3]);
      }
      asm volatile("v_permlane32_swap_b32 %0, %1" : "+v"(X0), "+v"(Y0));
      asm volatile("v_permlane32_swap_b32 %0, %1" : "+v"(X1), "+v"(Y1));
      u32x4 pw; pw[0] = X0; pw[1] = X1; pw[2] = Y0; pw[3] = Y1;
      pf[ks] = __builtin_bit_cast(half8, pw);
    }

    __builtin_amdgcn_s_setprio(1);
#pragma unroll
    for (int dt = 0; dt < 4; ++dt) {
      const int row = dt * 32 + c;
#pragma unroll
      for (int ks = 0; ks < 4; ++ks) {
        half8 vf = *(const half8*)&VsB[row * 64 + (((2 * ks + hi) ^ (row & 7)) * 8)];
        o[dt] = __builtin_amdgcn_mfma_f32_32x32x16_f16(vf, pf[ks], o[dt], 0, 0, 0);
      }
    }
    __builtin_amdgcn_s_setprio(0);
    __syncthreads();
  }

  const float inv = 1.f / ssum;
  const int b = bh >> 4, h = bh & 15;
  const size_t orow = ((size_t)(b * S + q0 + c)) * HD + h * D;
#pragma unroll
  for (int dt = 0; dt < 4; ++dt)
#pragma unroll
    for (int b2 = 0; b2 < 4; ++b2) {
      half4 h4;
#pragma unroll
      for (int a = 0; a < 4; ++a) h4[a] = (f16)(o[dt][4 * b2 + a] * inv);
      *(half4*)&O[orow + dt * 32 + 8 * b2 + 4 * hi] = h4;
    }
}

extern "C" void kernel_launch(void* const* d_in, const int* in_sizes, int n_in,
                              void* d_out, int out_size, void* d_ws, size_t ws_size,
                              hipStream_t stream) {
  (void)in_sizes; (void)n_in; (void)out_size; (void)ws_size;
  const float* hs = (const float*)d_in[0];
  const float* cosb = (const float*)d_in[1];
  const float* sinb = (const float*)d_in[2];
  const float* wq = (const float*)d_in[3];
  const float* wk = (const float*)d_in[4];
  const float* wv = (const float*)d_in[5];
  const float* wo = (const float*)d_in[6];
  float* out = (float*)d_out;
  char* ws = (char*)d_ws;
  f16* hs16 = (f16*)(ws);                 // 16M; dead after qkv384
  f16* attn = (f16*)(ws);                 // alias (written by flash)
  f16* wt   = (f16*)(ws + (16u << 20));   // 24M  [6144][2048]
  f16* wot  = (f16*)(ws + (40u << 20));   // 8M   [2048][2048]
  f16* Qb   = (f16*)(ws + (48u << 20));   // 16M  [32][2048][128]
  f16* Kb   = (f16*)(ws + (64u << 20));   // 16M
  f16* VtG  = (f16*)(ws + (80u << 20));   // 16M  [32][128][2048]
  f16* Vb   = (f16*)(ws + (96u << 20));   // 16M  [32][2048][128]

  cast_f32_f16<<<dim3(4096), dim3(256), 0, stream>>>(hs, hs16);
  transpose_cast<<<dim3(64, 64, 4), dim3(32, 8), 0, stream>>>(wq, wk, wv, wo, wt, wot);
  qkv384<<<dim3(256), dim3(512), 0, stream>>>(hs16, wt, cosb, sinb, Qb, Kb, Vb);
  transpose_v<<<dim3(1024), dim3(256), 0, stream>>>(Vb, VtG);
  flash_attn2<<<dim3(512), dim3(256), 0, stream>>>(Qb, Kb, VtG, attn);
  gemm_bt<float><<<dim3(512), dim3(256), 0, stream>>>(attn, wot, out, E, HD);
}

// Round 15
// 274.100 us; speedup vs baseline: 1.1784x; 1.1784x over previous
//
#include <hip/hip_runtime.h>
#include <stdint.h>

typedef _Float16 f16;
typedef _Float16 half8 __attribute__((ext_vector_type(8)));
typedef _Float16 half4 __attribute__((ext_vector_type(4)));
typedef __fp16 fp16x2 __attribute__((ext_vector_type(2)));
typedef float f32x4 __attribute__((ext_vector_type(4)));
typedef float f32x16 __attribute__((ext_vector_type(16)));
typedef uint32_t u32x4 __attribute__((ext_vector_type(4)));

static constexpr int Bsz = 2, S = 2048, E = 2048, H = 16, D = 128;
static constexpr int M = Bsz * S;        // 4096
static constexpr int N_QKV = 3 * H * D;  // 6144
static constexpr int HD = H * D;         // 2048

__device__ __forceinline__ void gload_lds16(const void* gp, void* lp) {
  __builtin_amdgcn_global_load_lds(
      (const __attribute__((address_space(1))) uint32_t*)(uintptr_t)gp,
      (__attribute__((address_space(3))) uint32_t*)(uint32_t)(uintptr_t)lp,
      16, 0, 0);
}

__device__ __forceinline__ uint32_t pkrtz(float a, float b) {
  fp16x2 r = __builtin_amdgcn_cvt_pkrtz(a, b);
  return __builtin_bit_cast(uint32_t, r);
}

// ---------- f32 -> f16 cast ----------
__global__ void cast_f32_f16(const float* __restrict__ in, f16* __restrict__ out) {
  size_t i = (size_t)(blockIdx.x * 256 + threadIdx.x) * 8;
  float4 a = *(const float4*)&in[i];
  float4 b = *(const float4*)&in[i + 4];
  half8 h;
  h[0] = (f16)a.x; h[1] = (f16)a.y; h[2] = (f16)a.z; h[3] = (f16)a.w;
  h[4] = (f16)b.x; h[5] = (f16)b.y; h[6] = (f16)b.z; h[7] = (f16)b.w;
  *(half8*)&out[i] = h;
}

// ---------- transpose 2048x2048 f32 [k][n] -> f16 [n][k] ----------
__global__ void transpose_cast(const float* __restrict__ wq, const float* __restrict__ wk,
                               const float* __restrict__ wv, const float* __restrict__ wo,
                               f16* __restrict__ wt, f16* __restrict__ wot) {
  __shared__ float tile[32][33];
  int z = blockIdx.z;
  const float* src = (z == 0) ? wq : (z == 1) ? wk : (z == 2) ? wv : wo;
  f16* dst = (z == 3) ? wot : wt + (size_t)z * E * HD;
  int bx = blockIdx.x * 32, by = blockIdx.y * 32;
  int tx = threadIdx.x, ty = threadIdx.y;
#pragma unroll
  for (int r = 0; r < 4; ++r)
    tile[ty + r * 8][tx] = src[(size_t)(by + ty + r * 8) * 2048 + bx + tx];
  __syncthreads();
#pragma unroll
  for (int r = 0; r < 4; ++r)
    dst[(size_t)(bx + ty + r * 8) * 2048 + by + tx] = (f16)tile[tx][ty + r * 8];
}

// Staging of one 32-k section.
#define STAGE4(PTR, BASE, KOFF, DST)                                       \
  gload_lds16(&PTR[BASE + (KOFF) + scol], &DST[t * 8]);                    \
  gload_lds16(&PTR[BASE + (size_t)64 * Kk + (KOFF) + scol], &DST[2048 + t * 8]);

// ---------- QKV GEMM (128x128, BK=64) + fused rope/split/v-transpose ----------
// Grid map: xcd = bid&7 owns bm in [xcd*4, xcd*4+4) (A panels 2MB, L2-resident);
// bn streams. bn 0..15: Q; 16..31: K (swapped mfma, rope in-register);
// 32..47: V (direct transposed store).
__global__ __launch_bounds__(256, 4) void qkv_fused(const f16* __restrict__ A,
                                                    const f16* __restrict__ Bt,
                                                    const float* __restrict__ cosb,
                                                    const float* __restrict__ sinb,
                                                    f16* __restrict__ Qb,
                                                    f16* __restrict__ Kb,
                                                    f16* __restrict__ VtG) {
  __shared__ f16 As[8192];  // [2 sections][128][32]
  __shared__ f16 Bs[8192];
  const int Kk = E;
  const int t = threadIdx.x, l = t & 63;
  const int wm = (t >> 7) & 1, wn = (t >> 6) & 1;
  const int lr = l & 15, g = l >> 4;
  const int bid = blockIdx.x;
  const int idx = bid >> 3;
  const int bm = (bid & 7) * 4 + (idx & 3);  // A-panel resident per XCD
  const int bn = idx >> 2;                   // 0..47, streamed
  const int srow = t >> 2;
  const int scol = (((t & 3) ^ (srow & 3)) * 8);
  const size_t abase = (size_t)(bm * 128 + srow) * Kk;
  const size_t bbase = (size_t)(bn * 128 + srow) * Kk;
  const int bt = bn >> 4;       // 0=q 1=k 2=v
  const int h = bn & 15;
  const int b = bm >> 4;
  const int bh = b * 16 + h;
  const int sblk = (bm & 15) * 128;
  f32x4 acc[4][4] = {};

  if (bt < 2) {
    // ---- Q/K: swapped-operand K-loop; wave cols {wn*32, +16, +64, +80} ----
    for (int k0 = 0; k0 < Kk; k0 += 64) {
      __syncthreads();
      STAGE4(A, abase, k0, As);
      STAGE4(Bt, bbase, k0, Bs);
      STAGE4(A, abase, k0 + 32, (As + 4096));
      STAGE4(Bt, bbase, k0 + 32, (Bs + 4096));
      __syncthreads();
#pragma unroll
      for (int kh = 0; kh < 2; ++kh) {
        const int so = kh * 4096;
        half8 af[4], bf[4];
#pragma unroll
        for (int i = 0; i < 4; ++i) {
          int ra = wm * 64 + i * 16 + lr;
          af[i] = *(const half8*)&As[so + ra * 32 + ((g ^ (ra & 3)) * 8)];
        }
#pragma unroll
        for (int j = 0; j < 4; ++j) {
          int rb = wn * 32 + (j & 1) * 16 + (j >> 1) * 64 + lr;
          bf[j] = *(const half8*)&Bs[so + rb * 32 + ((g ^ (rb & 3)) * 8)];
        }
#pragma unroll
        for (int i = 0; i < 4; ++i)
#pragma unroll
          for (int j = 0; j < 4; ++j)
            acc[i][j] = __builtin_amdgcn_mfma_f32_16x16x32_f16(bf[j], af[i], acc[i][j], 0, 0, 0);
      }
    }
    // ---- rope in-register, coalesced half4 stores ----
    f16* Dst = (bt == 0) ? Qb : Kb;
#pragma unroll
    for (int i = 0; i < 4; ++i) {
      const int s = sblk + wm * 64 + i * 16 + lr;
      const size_t obase = ((size_t)bh * S + s) * D;
      const size_t cbase = (size_t)s * D;
#pragma unroll
      for (int j = 0; j < 2; ++j) {
        const int dlo = wn * 32 + j * 16 + g * 4;
        float4 cl = *(const float4*)&cosb[cbase + dlo];
        float4 ch = *(const float4*)&cosb[cbase + dlo + 64];
        float4 sl = *(const float4*)&sinb[cbase + dlo];
        float4 sh = *(const float4*)&sinb[cbase + dlo + 64];
        float cla[4] = {cl.x, cl.y, cl.z, cl.w}, cha[4] = {ch.x, ch.y, ch.z, ch.w};
        float sla[4] = {sl.x, sl.y, sl.z, sl.w}, sha[4] = {sh.x, sh.y, sh.z, sh.w};
        half4 olo, ohi;
#pragma unroll
        for (int r = 0; r < 4; ++r) {
          float xl = acc[i][j][r], xh = acc[i][j + 2][r];
          olo[r] = (f16)(xl * cla[r] - xh * sla[r]);
          ohi[r] = (f16)(xh * cha[r] + xl * sha[r]);
        }
        *(half4*)&Dst[obase + dlo] = olo;
        *(half4*)&Dst[obase + dlo + 64] = ohi;
      }
    }
  } else {
    // ---- V: standard K-loop; direct transposed store ----
    for (int k0 = 0; k0 < Kk; k0 += 64) {
      __syncthreads();
      STAGE4(A, abase, k0, As);
      STAGE4(Bt, bbase, k0, Bs);
      STAGE4(A, abase, k0 + 32, (As + 4096));
      STAGE4(Bt, bbase, k0 + 32, (Bs + 4096));
      __syncthreads();
#pragma unroll
      for (int kh = 0; kh < 2; ++kh) {
        const int so = kh * 4096;
        half8 af[4], bf[4];
#pragma unroll
        for (int i = 0; i < 4; ++i) {
          int ra = wm * 64 + i * 16 + lr;
          int rb = wn * 64 + i * 16 + lr;
          af[i] = *(const half8*)&As[so + ra * 32 + ((g ^ (ra & 3)) * 8)];
          bf[i] = *(const half8*)&Bs[so + rb * 32 + ((g ^ (rb & 3)) * 8)];
        }
#pragma unroll
        for (int i = 0; i < 4; ++i)
#pragma unroll
          for (int j = 0; j < 4; ++j)
            acc[i][j] = __builtin_amdgcn_mfma_f32_16x16x32_f16(af[i], bf[j], acc[i][j], 0, 0, 0);
      }
    }
#pragma unroll
    for (int j = 0; j < 4; ++j) {
      int d = wn * 64 + j * 16 + lr;
      size_t rowb = ((size_t)bh * D + d) * S;
#pragma unroll
      for (int i = 0; i < 4; ++i) {
        int s0 = sblk + wm * 64 + i * 16 + g * 4;
        half4 h4;
#pragma unroll
        for (int r = 0; r < 4; ++r) h4[r] = (f16)acc[i][j][r];
        *(half4*)&VtG[rowb + s0] = h4;
      }
    }
  }
}

// ---------- out-proj GEMM: 128x128 BK=64; bm L2-resident per XCD ----------
template <typename OutT>
__global__ __launch_bounds__(256, 4) void gemm_bt(const f16* __restrict__ A,
                                                  const f16* __restrict__ Bt,
                                                  OutT* __restrict__ C,
                                                  int Nn, int Kk) {
  __shared__ f16 As[8192];
  __shared__ f16 Bs[8192];
  const int t = threadIdx.x, l = t & 63;
  const int wm = (t >> 7) & 1, wn = (t >> 6) & 1;
  const int bid = blockIdx.x;
  const int bm = (bid & 7) * 4 + ((bid >> 3) & 3);  // 0..31
  const int bn = bid >> 5;                          // 0..15
  const int lr = l & 15, g = l >> 4;
  const int srow = t >> 2;
  const int scol = (((t & 3) ^ (srow & 3)) * 8);
  const size_t abase = (size_t)(bm * 128 + srow) * Kk;
  const size_t bbase = (size_t)(bn * 128 + srow) * Kk;
  f32x4 acc[4][4] = {};
  for (int k0 = 0; k0 < Kk; k0 += 64) {
    __syncthreads();
    STAGE4(A, abase, k0, As);
    STAGE4(Bt, bbase, k0, Bs);
    STAGE4(A, abase, k0 + 32, (As + 4096));
    STAGE4(Bt, bbase, k0 + 32, (Bs + 4096));
    __syncthreads();
#pragma unroll
    for (int kh = 0; kh < 2; ++kh) {
      const int so = kh * 4096;
      half8 af[4], bf[4];
#pragma unroll
      for (int i = 0; i < 4; ++i) {
        int ra = wm * 64 + i * 16 + lr;
        int rb = wn * 64 + i * 16 + lr;
        af[i] = *(const half8*)&As[so + ra * 32 + ((g ^ (ra & 3)) * 8)];
        bf[i] = *(const half8*)&Bs[so + rb * 32 + ((g ^ (rb & 3)) * 8)];
      }
#pragma unroll
      for (int i = 0; i < 4; ++i)
#pragma unroll
        for (int j = 0; j < 4; ++j)
          acc[i][j] = __builtin_amdgcn_mfma_f32_16x16x32_f16(af[i], bf[j], acc[i][j], 0, 0, 0);
    }
  }
#pragma unroll
  for (int i = 0; i < 4; ++i)
#pragma unroll
    for (int j = 0; j < 4; ++j) {
      int row = bm * 128 + wm * 64 + i * 16 + g * 4;
      int col = bn * 128 + wn * 64 + j * 16 + lr;
#pragma unroll
      for (int r = 0; r < 4; ++r)
        C[(size_t)(row + r) * Nn + col] = (OutT)acc[i][j][r];
    }
}

// ---------- flash attention: 32x32x16, swapped operands, defer-max ----------
__device__ __forceinline__ void stage_kv(const f16* __restrict__ Kg, const f16* __restrict__ Vg,
                                         f16* KsB, f16* VsB, int t, int kv) {
#pragma unroll
  for (int rnd = 0; rnd < 4; ++rnd) {
    int row = rnd * 16 + (t >> 4);
    int c = t & 15;
    gload_lds16(&Kg[(size_t)(kv + row) * D + ((c ^ (row & 7)) * 8)], &KsB[rnd * 2048 + t * 8]);
  }
#pragma unroll
  for (int rnd = 0; rnd < 4; ++rnd) {
    int row = rnd * 32 + (t >> 3);
    int c = t & 7;
    gload_lds16(&Vg[(size_t)row * S + kv + ((c ^ (row & 7)) * 8)], &VsB[rnd * 2048 + t * 8]);
  }
}

__global__ __launch_bounds__(256, 2) void flash_attn2(const f16* __restrict__ Q,
                                                      const f16* __restrict__ K,
                                                      const f16* __restrict__ Vt,
                                                      f16* __restrict__ O) {
  __shared__ f16 lds[2][16384];
  const int t = threadIdx.x, l = t & 63, w = t >> 6;
  const int c = l & 31, hi = l >> 5;
  int bid = blockIdx.x;
  bid = (bid & 7) * 64 + (bid >> 3);
  const int bh = bid >> 4, qt = bid & 15;
  const size_t baseQ = (size_t)bh * S * D;
  const f16* Kg = K + baseQ;
  const f16* Vg = Vt + (size_t)bh * D * S;
  const int q0 = qt * 128 + w * 32;
  half8 qf[8];
#pragma unroll
  for (int dc = 0; dc < 8; ++dc)
    qf[dc] = *(const half8*)&Q[baseQ + (size_t)(q0 + c) * D + dc * 16 + hi * 8];
  f32x16 o[4] = {};
  float m = -3.0e38f, ssum = 0.f;

  stage_kv(Kg, Vg, &lds[0][0], &lds[0][8192], t, 0);
  __syncthreads();

  for (int it = 0; it < S / 64; ++it) {
    const int cur = it & 1;
    const f16* KsB = &lds[cur][0];
    const f16* VsB = &lds[cur][8192];
    if (it + 1 < S / 64) stage_kv(Kg, Vg, &lds[cur ^ 1][0], &lds[cur ^ 1][8192], t, (it + 1) * 64);

    f32x16 s0 = {}, s1 = {};
    __builtin_amdgcn_s_setprio(1);
#pragma unroll
    for (int dc = 0; dc < 8; ++dc) {
      const int r0 = c, r1 = 32 + c;
      half8 kf0 = *(const half8*)&KsB[r0 * 128 + (((2 * dc + hi) ^ (r0 & 7)) * 8)];
      half8 kf1 = *(const half8*)&KsB[r1 * 128 + (((2 * dc + hi) ^ (r1 & 7)) * 8)];
      s0 = __builtin_amdgcn_mfma_f32_32x32x16_f16(kf0, qf[dc], s0, 0, 0, 0);
      s1 = __builtin_amdgcn_mfma_f32_32x32x16_f16(kf1, qf[dc], s1, 0, 0, 0);
    }
    __builtin_amdgcn_s_setprio(0);

    float tm = s0[0];
#pragma unroll
    for (int r = 1; r < 16; ++r) tm = fmaxf(tm, s0[r]);
#pragma unroll
    for (int r = 0; r < 16; ++r) tm = fmaxf(tm, s1[r]);
    tm = fmaxf(tm, __shfl_xor(tm, 32));
    // defer-max (T13): only rescale when some lane's tile max exceeds m+8
    if (!__all(tm <= m + 8.f)) {
      float mn = fmaxf(m, tm);
      float corr = __expf(m - mn);
      m = mn;
      ssum *= corr;
#pragma unroll
      for (int dt = 0; dt < 4; ++dt)
#pragma unroll
        for (int r = 0; r < 16; ++r) o[dt][r] *= corr;
    }
    float ts = 0.f;
#pragma unroll
    for (int r = 0; r < 16; ++r) { s0[r] = __expf(s0[r] - m); ts += s0[r]; }
#pragma unroll
    for (int r = 0; r < 16; ++r) { s1[r] = __expf(s1[r] - m); ts += s1[r]; }
    ts += __shfl_xor(ts, 32);
    ssum += ts;

    half8 pf[4];
#pragma unroll
    for (int ks = 0; ks < 4; ++ks) {
      const int B0 = 2 * (ks & 1), B1 = B0 + 1;
      uint32_t X0, X1, Y0, Y1;
      if (ks < 2) {
        X0 = pkrtz(s0[4 * B0 + 0], s0[4 * B0 + 1]);
        X1 = pkrtz(s0[4 * B0 + 2], s0[4 * B0 + 3]);
        Y0 = pkrtz(s0[4 * B1 + 0], s0[4 * B1 + 1]);
        Y1 = pkrtz(s0[4 * B1 + 2], s0[4 * B1 + 3]);
      } else {
        X0 = pkrtz(s1[4 * B0 + 0], s1[4 * B0 + 1]);
        X1 = pkrtz(s1[4 * B0 + 2], s1[4 * B0 + 3]);
        Y0 = pkrtz(s1[4 * B1 + 0], s1[4 * B1 + 1]);
        Y1 = pkrtz(s1[4 * B1 + 2], s1[4 * B1 + 3]);
      }
      asm volatile("v_permlane32_swap_b32 %0, %1" : "+v"(X0), "+v"(Y0));
      asm volatile("v_permlane32_swap_b32 %0, %1" : "+v"(X1), "+v"(Y1));
      u32x4 pw; pw[0] = X0; pw[1] = X1; pw[2] = Y0; pw[3] = Y1;
      pf[ks] = __builtin_bit_cast(half8, pw);
    }

    __builtin_amdgcn_s_setprio(1);
#pragma unroll
    for (int dt = 0; dt < 4; ++dt) {
      const int row = dt * 32 + c;
#pragma unroll
      for (int ks = 0; ks < 4; ++ks) {
        half8 vf = *(const half8*)&VsB[row * 64 + (((2 * ks + hi) ^ (row & 7)) * 8)];
        o[dt] = __builtin_amdgcn_mfma_f32_32x32x16_f16(vf, pf[ks], o[dt], 0, 0, 0);
      }
    }
    __builtin_amdgcn_s_setprio(0);
    __syncthreads();
  }

  const float inv = 1.f / ssum;
  const int b = bh >> 4, h = bh & 15;
  const size_t orow = ((size_t)(b * S + q0 + c)) * HD + h * D;
#pragma unroll
  for (int dt = 0; dt < 4; ++dt)
#pragma unroll
    for (int b2 = 0; b2 < 4; ++b2) {
      half4 h4;
#pragma unroll
      for (int a = 0; a < 4; ++a) h4[a] = (f16)(o[dt][4 * b2 + a] * inv);
      *(half4*)&O[orow + dt * 32 + 8 * b2 + 4 * hi] = h4;
    }
}

extern "C" void kernel_launch(void* const* d_in, const int* in_sizes, int n_in,
                              void* d_out, int out_size, void* d_ws, size_t ws_size,
                              hipStream_t stream) {
  (void)in_sizes; (void)n_in; (void)out_size; (void)ws_size;
  const float* hs = (const float*)d_in[0];
  const float* cosb = (const float*)d_in[1];
  const float* sinb = (const float*)d_in[2];
  const float* wq = (const float*)d_in[3];
  const float* wk = (const float*)d_in[4];
  const float* wv = (const float*)d_in[5];
  const float* wo = (const float*)d_in[6];
  float* out = (float*)d_out;
  char* ws = (char*)d_ws;
  f16* hs16 = (f16*)(ws);                 // 16M; dead after qkv_fused
  f16* attn = (f16*)(ws);                 // 16M; alias (written by flash)
  f16* wt   = (f16*)(ws + (16u << 20));   // 24M  [6144][2048]
  f16* wot  = (f16*)(ws + (40u << 20));   // 8M   [2048][2048]
  f16* Qb   = (f16*)(ws + (48u << 20));   // 16M  [32][2048][128]
  f16* Kb   = (f16*)(ws + (64u << 20));   // 16M  [32][2048][128]
  f16* VtG  = (f16*)(ws + (80u << 20));   // 16M  [32][128][2048]

  cast_f32_f16<<<dim3(4096), dim3(256), 0, stream>>>(hs, hs16);
  transpose_cast<<<dim3(64, 64, 4), dim3(32, 8), 0, stream>>>(wq, wk, wv, wo, wt, wot);
  qkv_fused<<<dim3(1536), dim3(256), 0, stream>>>(hs16, wt, cosb, sinb, Qb, Kb, VtG);
  flash_attn2<<<dim3(512), dim3(256), 0, stream>>>(Qb, Kb, VtG, attn);
  gemm_bt<float><<<dim3(512), dim3(256), 0, stream>>>(attn, wot, out, E, HD);
}

// Round 16
// 272.241 us; speedup vs baseline: 1.1864x; 1.0068x over previous
//
#include <hip/hip_runtime.h>
#include <stdint.h>

typedef _Float16 f16;
typedef _Float16 half8 __attribute__((ext_vector_type(8)));
typedef _Float16 half4 __attribute__((ext_vector_type(4)));
typedef __fp16 fp16x2 __attribute__((ext_vector_type(2)));
typedef float f32x4 __attribute__((ext_vector_type(4)));
typedef float f32x16 __attribute__((ext_vector_type(16)));
typedef uint32_t u32x4 __attribute__((ext_vector_type(4)));

static constexpr int Bsz = 2, S = 2048, E = 2048, H = 16, D = 128;
static constexpr int M = Bsz * S;        // 4096
static constexpr int N_QKV = 3 * H * D;  // 6144
static constexpr int HD = H * D;         // 2048

__device__ __forceinline__ void gload_lds16(const void* gp, void* lp) {
  __builtin_amdgcn_global_load_lds(
      (const __attribute__((address_space(1))) uint32_t*)(uintptr_t)gp,
      (__attribute__((address_space(3))) uint32_t*)(uint32_t)(uintptr_t)lp,
      16, 0, 0);
}

__device__ __forceinline__ uint32_t pkrtz(float a, float b) {
  fp16x2 r = __builtin_amdgcn_cvt_pkrtz(a, b);
  return __builtin_bit_cast(uint32_t, r);
}

// ---------- f32 -> f16 cast ----------
__global__ void cast_f32_f16(const float* __restrict__ in, f16* __restrict__ out) {
  size_t i = (size_t)(blockIdx.x * 256 + threadIdx.x) * 8;
  float4 a = *(const float4*)&in[i];
  float4 b = *(const float4*)&in[i + 4];
  half8 h;
  h[0] = (f16)a.x; h[1] = (f16)a.y; h[2] = (f16)a.z; h[3] = (f16)a.w;
  h[4] = (f16)b.x; h[5] = (f16)b.y; h[6] = (f16)b.z; h[7] = (f16)b.w;
  *(half8*)&out[i] = h;
}

// ---------- transpose 2048x2048 f32 [k][n] -> f16 [n][k] ----------
__global__ void transpose_cast(const float* __restrict__ wq, const float* __restrict__ wk,
                               const float* __restrict__ wv, const float* __restrict__ wo,
                               f16* __restrict__ wt, f16* __restrict__ wot) {
  __shared__ float tile[32][33];
  int z = blockIdx.z;
  const float* src = (z == 0) ? wq : (z == 1) ? wk : (z == 2) ? wv : wo;
  f16* dst = (z == 3) ? wot : wt + (size_t)z * E * HD;
  int bx = blockIdx.x * 32, by = blockIdx.y * 32;
  int tx = threadIdx.x, ty = threadIdx.y;
#pragma unroll
  for (int r = 0; r < 4; ++r)
    tile[ty + r * 8][tx] = src[(size_t)(by + ty + r * 8) * 2048 + bx + tx];
  __syncthreads();
#pragma unroll
  for (int r = 0; r < 4; ++r)
    dst[(size_t)(bx + ty + r * 8) * 2048 + by + tx] = (f16)tile[tx][ty + r * 8];
}

// Staging of one 32-k section into DST (linear lane order).
#define STAGE4(PTR, BASE, KOFF, DST)                                       \
  gload_lds16(&PTR[BASE + (KOFF) + scol], &DST[t * 8]);                    \
  gload_lds16(&PTR[BASE + (size_t)64 * Kk + (KOFF) + scol], &DST[2048 + t * 8]);

// Stage one full 64-k tile (8 gloads) into buffer bb.
#define STAGE_TILE(k0_, bb_)                                               \
  do {                                                                     \
    STAGE4(A, abase, (k0_), (As + (bb_)*8192));                            \
    STAGE4(Bt, bbase, (k0_), (Bs + (bb_)*8192));                           \
    STAGE4(A, abase, (k0_) + 32, (As + (bb_)*8192 + 4096));                \
    STAGE4(Bt, bbase, (k0_) + 32, (Bs + (bb_)*8192 + 4096));               \
  } while (0)
#define PIPE_END()                                             \
  asm volatile("s_waitcnt vmcnt(0)" ::: "memory");             \
  __builtin_amdgcn_s_barrier()

// ---------- QKV GEMM (128x128, BK=64, T3-minimum double-buffer) + fused
// rope/split/v-transpose. bn 0..15 Q; 16..31 K (swapped mfma, in-reg rope);
// 32..47 V (direct transposed store). bm L2-resident per XCD.
__global__ __launch_bounds__(256, 2) void qkv_fused(const f16* __restrict__ A,
                                                    const f16* __restrict__ Bt,
                                                    const float* __restrict__ cosb,
                                                    const float* __restrict__ sinb,
                                                    f16* __restrict__ Qb,
                                                    f16* __restrict__ Kb,
                                                    f16* __restrict__ VtG) {
  __shared__ f16 As[16384];  // [2 buf][2 sections][128][32]
  __shared__ f16 Bs[16384];
  const int Kk = E;
  const int t = threadIdx.x, l = t & 63;
  const int wm = (t >> 7) & 1, wn = (t >> 6) & 1;
  const int lr = l & 15, g = l >> 4;
  const int bid = blockIdx.x;
  const int idx = bid >> 3;
  const int bm = (bid & 7) * 4 + (idx & 3);  // A-panel resident per XCD
  const int bn = idx >> 2;                   // 0..47, streamed
  const int srow = t >> 2;
  const int scol = (((t & 3) ^ (srow & 3)) * 8);
  const size_t abase = (size_t)(bm * 128 + srow) * Kk;
  const size_t bbase = (size_t)(bn * 128 + srow) * Kk;
  const int bt = bn >> 4;       // 0=q 1=k 2=v
  const int h = bn & 15;
  const int b = bm >> 4;
  const int bh = b * 16 + h;
  const int sblk = (bm & 15) * 128;
  f32x4 acc[4][4] = {};

  STAGE_TILE(0, 0);
  PIPE_END();

  if (bt < 2) {
    // ---- Q/K: swapped-operand K-loop; wave cols {wn*32, +16, +64, +80} ----
    for (int T = 0; T < 32; ++T) {
      const int cb = T & 1;
      if (T + 1 < 32) STAGE_TILE((T + 1) * 64, cb ^ 1);
#pragma unroll
      for (int kh = 0; kh < 2; ++kh) {
        const int so = cb * 8192 + kh * 4096;
        half8 af[4], bf[4];
#pragma unroll
        for (int i = 0; i < 4; ++i) {
          int ra = wm * 64 + i * 16 + lr;
          af[i] = *(const half8*)&As[so + ra * 32 + ((g ^ (ra & 3)) * 8)];
        }
#pragma unroll
        for (int j = 0; j < 4; ++j) {
          int rb = wn * 32 + (j & 1) * 16 + (j >> 1) * 64 + lr;
          bf[j] = *(const half8*)&Bs[so + rb * 32 + ((g ^ (rb & 3)) * 8)];
        }
#pragma unroll
        for (int i = 0; i < 4; ++i)
#pragma unroll
          for (int j = 0; j < 4; ++j)
            acc[i][j] = __builtin_amdgcn_mfma_f32_16x16x32_f16(bf[j], af[i], acc[i][j], 0, 0, 0);
      }
      if (T + 1 < 32) { PIPE_END(); }
    }
    // ---- rope in-register, coalesced half4 stores ----
    f16* Dst = (bt == 0) ? Qb : Kb;
#pragma unroll
    for (int i = 0; i < 4; ++i) {
      const int s = sblk + wm * 64 + i * 16 + lr;
      const size_t obase = ((size_t)bh * S + s) * D;
      const size_t cbase = (size_t)s * D;
#pragma unroll
      for (int j = 0; j < 2; ++j) {
        const int dlo = wn * 32 + j * 16 + g * 4;
        float4 cl = *(const float4*)&cosb[cbase + dlo];
        float4 ch = *(const float4*)&cosb[cbase + dlo + 64];
        float4 sl = *(const float4*)&sinb[cbase + dlo];
        float4 sh = *(const float4*)&sinb[cbase + dlo + 64];
        float cla[4] = {cl.x, cl.y, cl.z, cl.w}, cha[4] = {ch.x, ch.y, ch.z, ch.w};
        float sla[4] = {sl.x, sl.y, sl.z, sl.w}, sha[4] = {sh.x, sh.y, sh.z, sh.w};
        half4 olo, ohi;
#pragma unroll
        for (int r = 0; r < 4; ++r) {
          float xl = acc[i][j][r], xh = acc[i][j + 2][r];
          olo[r] = (f16)(xl * cla[r] - xh * sla[r]);
          ohi[r] = (f16)(xh * cha[r] + xl * sha[r]);
        }
        *(half4*)&Dst[obase + dlo] = olo;
        *(half4*)&Dst[obase + dlo + 64] = ohi;
      }
    }
  } else {
    // ---- V: standard K-loop; direct transposed store ----
    for (int T = 0; T < 32; ++T) {
      const int cb = T & 1;
      if (T + 1 < 32) STAGE_TILE((T + 1) * 64, cb ^ 1);
#pragma unroll
      for (int kh = 0; kh < 2; ++kh) {
        const int so = cb * 8192 + kh * 4096;
        half8 af[4], bf[4];
#pragma unroll
        for (int i = 0; i < 4; ++i) {
          int ra = wm * 64 + i * 16 + lr;
          int rb = wn * 64 + i * 16 + lr;
          af[i] = *(const half8*)&As[so + ra * 32 + ((g ^ (ra & 3)) * 8)];
          bf[i] = *(const half8*)&Bs[so + rb * 32 + ((g ^ (rb & 3)) * 8)];
        }
#pragma unroll
        for (int i = 0; i < 4; ++i)
#pragma unroll
          for (int j = 0; j < 4; ++j)
            acc[i][j] = __builtin_amdgcn_mfma_f32_16x16x32_f16(af[i], bf[j], acc[i][j], 0, 0, 0);
      }
      if (T + 1 < 32) { PIPE_END(); }
    }
#pragma unroll
    for (int j = 0; j < 4; ++j) {
      int d = wn * 64 + j * 16 + lr;
      size_t rowb = ((size_t)bh * D + d) * S;
#pragma unroll
      for (int i = 0; i < 4; ++i) {
        int s0 = sblk + wm * 64 + i * 16 + g * 4;
        half4 h4;
#pragma unroll
        for (int r = 0; r < 4; ++r) h4[r] = (f16)acc[i][j][r];
        *(half4*)&VtG[rowb + s0] = h4;
      }
    }
  }
}

// ---------- out-proj GEMM: 128x128 BK=64, T3-minimum double-buffer ----------
template <typename OutT>
__global__ __launch_bounds__(256, 2) void gemm_bt(const f16* __restrict__ A,
                                                  const f16* __restrict__ Bt,
                                                  OutT* __restrict__ C,
                                                  int Nn, int Kk) {
  __shared__ f16 As[16384];
  __shared__ f16 Bs[16384];
  const int t = threadIdx.x, l = t & 63;
  const int wm = (t >> 7) & 1, wn = (t >> 6) & 1;
  const int bid = blockIdx.x;
  const int bm = (bid & 7) * 4 + ((bid >> 3) & 3);  // 0..31
  const int bn = bid >> 5;                          // 0..15
  const int lr = l & 15, g = l >> 4;
  const int srow = t >> 2;
  const int scol = (((t & 3) ^ (srow & 3)) * 8);
  const size_t abase = (size_t)(bm * 128 + srow) * Kk;
  const size_t bbase = (size_t)(bn * 128 + srow) * Kk;
  f32x4 acc[4][4] = {};
  const int NT = Kk >> 6;

  STAGE_TILE(0, 0);
  PIPE_END();

  for (int T = 0; T < NT; ++T) {
    const int cb = T & 1;
    if (T + 1 < NT) STAGE_TILE((T + 1) * 64, cb ^ 1);
#pragma unroll
    for (int kh = 0; kh < 2; ++kh) {
      const int so = cb * 8192 + kh * 4096;
      half8 af[4], bf[4];
#pragma unroll
      for (int i = 0; i < 4; ++i) {
        int ra = wm * 64 + i * 16 + lr;
        int rb = wn * 64 + i * 16 + lr;
        af[i] = *(const half8*)&As[so + ra * 32 + ((g ^ (ra & 3)) * 8)];
        bf[i] = *(const half8*)&Bs[so + rb * 32 + ((g ^ (rb & 3)) * 8)];
      }
#pragma unroll
      for (int i = 0; i < 4; ++i)
#pragma unroll
        for (int j = 0; j < 4; ++j)
          acc[i][j] = __builtin_amdgcn_mfma_f32_16x16x32_f16(af[i], bf[j], acc[i][j], 0, 0, 0);
    }
    if (T + 1 < NT) { PIPE_END(); }
  }
#pragma unroll
  for (int i = 0; i < 4; ++i)
#pragma unroll
    for (int j = 0; j < 4; ++j) {
      int row = bm * 128 + wm * 64 + i * 16 + g * 4;
      int col = bn * 128 + wn * 64 + j * 16 + lr;
#pragma unroll
      for (int r = 0; r < 4; ++r)
        C[(size_t)(row + r) * Nn + col] = (OutT)acc[i][j][r];
    }
}

// ---------- flash attention: 32x32x16, swapped operands, defer-max ----------
__device__ __forceinline__ void stage_kv(const f16* __restrict__ Kg, const f16* __restrict__ Vg,
                                         f16* KsB, f16* VsB, int t, int kv) {
#pragma unroll
  for (int rnd = 0; rnd < 4; ++rnd) {
    int row = rnd * 16 + (t >> 4);
    int c = t & 15;
    gload_lds16(&Kg[(size_t)(kv + row) * D + ((c ^ (row & 7)) * 8)], &KsB[rnd * 2048 + t * 8]);
  }
#pragma unroll
  for (int rnd = 0; rnd < 4; ++rnd) {
    int row = rnd * 32 + (t >> 3);
    int c = t & 7;
    gload_lds16(&Vg[(size_t)row * S + kv + ((c ^ (row & 7)) * 8)], &VsB[rnd * 2048 + t * 8]);
  }
}

__global__ __launch_bounds__(256, 2) void flash_attn2(const f16* __restrict__ Q,
                                                      const f16* __restrict__ K,
                                                      const f16* __restrict__ Vt,
                                                      f16* __restrict__ O) {
  __shared__ f16 lds[2][16384];
  const int t = threadIdx.x, l = t & 63, w = t >> 6;
  const int c = l & 31, hi = l >> 5;
  int bid = blockIdx.x;
  bid = (bid & 7) * 64 + (bid >> 3);
  const int bh = bid >> 4, qt = bid & 15;
  const size_t baseQ = (size_t)bh * S * D;
  const f16* Kg = K + baseQ;
  const f16* Vg = Vt + (size_t)bh * D * S;
  const int q0 = qt * 128 + w * 32;
  half8 qf[8];
#pragma unroll
  for (int dc = 0; dc < 8; ++dc)
    qf[dc] = *(const half8*)&Q[baseQ + (size_t)(q0 + c) * D + dc * 16 + hi * 8];
  f32x16 o[4] = {};
  float m = -3.0e38f, ssum = 0.f;

  stage_kv(Kg, Vg, &lds[0][0], &lds[0][8192], t, 0);
  __syncthreads();

  for (int it = 0; it < S / 64; ++it) {
    const int cur = it & 1;
    const f16* KsB = &lds[cur][0];
    const f16* VsB = &lds[cur][8192];
    if (it + 1 < S / 64) stage_kv(Kg, Vg, &lds[cur ^ 1][0], &lds[cur ^ 1][8192], t, (it + 1) * 64);

    f32x16 s0 = {}, s1 = {};
    __builtin_amdgcn_s_setprio(1);
#pragma unroll
    for (int dc = 0; dc < 8; ++dc) {
      const int r0 = c, r1 = 32 + c;
      half8 kf0 = *(const half8*)&KsB[r0 * 128 + (((2 * dc + hi) ^ (r0 & 7)) * 8)];
      half8 kf1 = *(const half8*)&KsB[r1 * 128 + (((2 * dc + hi) ^ (r1 & 7)) * 8)];
      s0 = __builtin_amdgcn_mfma_f32_32x32x16_f16(kf0, qf[dc], s0, 0, 0, 0);
      s1 = __builtin_amdgcn_mfma_f32_32x32x16_f16(kf1, qf[dc], s1, 0, 0, 0);
    }
    __builtin_amdgcn_s_setprio(0);

    float tm = s0[0];
#pragma unroll
    for (int r = 1; r < 16; ++r) tm = fmaxf(tm, s0[r]);
#pragma unroll
    for (int r = 0; r < 16; ++r) tm = fmaxf(tm, s1[r]);
    tm = fmaxf(tm, __shfl_xor(tm, 32));
    if (!__all(tm <= m + 8.f)) {
      float mn = fmaxf(m, tm);
      float corr = __expf(m - mn);
      m = mn;
      ssum *= corr;
#pragma unroll
      for (int dt = 0; dt < 4; ++dt)
#pragma unroll
        for (int r = 0; r < 16; ++r) o[dt][r] *= corr;
    }
    float ts = 0.f;
#pragma unroll
    for (int r = 0; r < 16; ++r) { s0[r] = __expf(s0[r] - m); ts += s0[r]; }
#pragma unroll
    for (int r = 0; r < 16; ++r) { s1[r] = __expf(s1[r] - m); ts += s1[r]; }
    ts += __shfl_xor(ts, 32);
    ssum += ts;

    half8 pf[4];
#pragma unroll
    for (int ks = 0; ks < 4; ++ks) {
      const int B0 = 2 * (ks & 1), B1 = B0 + 1;
      uint32_t X0, X1, Y0, Y1;
      if (ks < 2) {
        X0 = pkrtz(s0[4 * B0 + 0], s0[4 * B0 + 1]);
        X1 = pkrtz(s0[4 * B0 + 2], s0[4 * B0 + 3]);
        Y0 = pkrtz(s0[4 * B1 + 0], s0[4 * B1 + 1]);
        Y1 = pkrtz(s0[4 * B1 + 2], s0[4 * B1 + 3]);
      } else {
        X0 = pkrtz(s1[4 * B0 + 0], s1[4 * B0 + 1]);
        X1 = pkrtz(s1[4 * B0 + 2], s1[4 * B0 + 3]);
        Y0 = pkrtz(s1[4 * B1 + 0], s1[4 * B1 + 1]);
        Y1 = pkrtz(s1[4 * B1 + 2], s1[4 * B1 + 3]);
      }
      asm volatile("v_permlane32_swap_b32 %0, %1" : "+v"(X0), "+v"(Y0));
      asm volatile("v_permlane32_swap_b32 %0, %1" : "+v"(X1), "+v"(Y1));
      u32x4 pw; pw[0] = X0; pw[1] = X1; pw[2] = Y0; pw[3] = Y1;
      pf[ks] = __builtin_bit_cast(half8, pw);
    }

    __builtin_amdgcn_s_setprio(1);
#pragma unroll
    for (int dt = 0; dt < 4; ++dt) {
      const int row = dt * 32 + c;
#pragma unroll
      for (int ks = 0; ks < 4; ++ks) {
        half8 vf = *(const half8*)&VsB[row * 64 + (((2 * ks + hi) ^ (row & 7)) * 8)];
        o[dt] = __builtin_amdgcn_mfma_f32_32x32x16_f16(vf, pf[ks], o[dt], 0, 0, 0);
      }
    }
    __builtin_amdgcn_s_setprio(0);
    __syncthreads();
  }

  const float inv = 1.f / ssum;
  const int b = bh >> 4, h = bh & 15;
  const size_t orow = ((size_t)(b * S + q0 + c)) * HD + h * D;
#pragma unroll
  for (int dt = 0; dt < 4; ++dt)
#pragma unroll
    for (int b2 = 0; b2 < 4; ++b2) {
      half4 h4;
#pragma unroll
      for (int a = 0; a < 4; ++a) h4[a] = (f16)(o[dt][4 * b2 + a] * inv);
      *(half4*)&O[orow + dt * 32 + 8 * b2 + 4 * hi] = h4;
    }
}

extern "C" void kernel_launch(void* const* d_in, const int* in_sizes, int n_in,
                              void* d_out, int out_size, void* d_ws, size_t ws_size,
                              hipStream_t stream) {
  (void)in_sizes; (void)n_in; (void)out_size; (void)ws_size;
  const float* hs = (const float*)d_in[0];
  const float* cosb = (const float*)d_in[1];
  const float* sinb = (const float*)d_in[2];
  const float* wq = (const float*)d_in[3];
  const float* wk = (const float*)d_in[4];
  const float* wv = (const float*)d_in[5];
  const float* wo = (const float*)d_in[6];
  float* out = (float*)d_out;
  char* ws = (char*)d_ws;
  f16* hs16 = (f16*)(ws);                 // 16M; dead after qkv_fused
  f16* attn = (f16*)(ws);                 // 16M; alias (written by flash)
  f16* wt   = (f16*)(ws + (16u << 20));   // 24M  [6144][2048]
  f16* wot  = (f16*)(ws + (40u << 20));   // 8M   [2048][2048]
  f16* Qb   = (f16*)(ws + (48u << 20));   // 16M  [32][2048][128]
  f16* Kb   = (f16*)(ws + (64u << 20));   // 16M  [32][2048][128]
  f16* VtG  = (f16*)(ws + (80u << 20));   // 16M  [32][128][2048]

  cast_f32_f16<<<dim3(4096), dim3(256), 0, stream>>>(hs, hs16);
  transpose_cast<<<dim3(64, 64, 4), dim3(32, 8), 0, stream>>>(wq, wk, wv, wo, wt, wot);
  qkv_fused<<<dim3(1536), dim3(256), 0, stream>>>(hs16, wt, cosb, sinb, Qb, Kb, VtG);
  flash_attn2<<<dim3(512), dim3(256), 0, stream>>>(Qb, Kb, VtG, attn);
  gemm_bt<float><<<dim3(512), dim3(256), 0, stream>>>(attn, wot, out, E, HD);
}